// Round 9
// baseline (107.906 us; speedup 1.0000x reference)
//
#include <hip/hip_runtime.h>

// ConjunctionLayer: out[b,j] = -1 / (-1 + sum_i log(1 - (1-x[b,i]) * W[j,i]))
// B=4096, INPUT_DIM=512, N=128, fp32.
//
// R9: evict x from VMEM. R3b..R8 showed insensitivity to occupancy, packing,
// log count, gather volume -> dominant term = steady-state x vector-load
// stream (256 loads/wave, L2 latency, distance-1 prefetch). Now:
//  - x staged ONCE per block into LDS: 16 rows = 32 KB contiguous global ->
//    512 threads x 4 coalesced dwordx4. Hot loop has ZERO global loads.
//  - x read back as wave-uniform ds_read_b128 (broadcast, conflict-free,
//    ~120 cyc) with an explicit distance-2 A/B register double-buffer
//    (named float4 regs, no arrays -> no SROA/scratch risk).
//  - scalar fma/mul chain; w[64],u[64]=1-w resident, accessed only with
//    template-constant indices via array-reference (register-promotable).
//  - product-of-64 -> one v_log_f32 per bi (>= 0.5^64 ~ 5e-20, normal fp32).
// Mapping: lane<->j (64 j, half h), wave<->K-chunk (8 x 64 i), NB=16,
// 512 blocks x 512 thr, LDS 64 KB (32 x-stage + 32 partials), 2 blocks/CU.

typedef float v4f __attribute__((ext_vector_type(4)));

constexpr int IDIM  = 512;
constexpr int NOUT  = 128;
constexpr int BTOT  = 4096;
constexpr int KC    = 64;            // i per wave
constexpr int NB    = 16;            // b per block
constexpr int GB    = BTOT / NB;     // 256 b-groups
constexpr float LN2 = 0.69314718055994530942f;

// 16-i chunk -> scalar partial product. 16 v_fma_f32 + 15 v_mul_f32.
// C = chunk index within the wave's 64-i fragment (constant -> w/u indices
// constant -> arrays stay in registers).
template<int C>
__device__ __forceinline__ float chunk16s(float4 a0, float4 a1, float4 a2, float4 a3,
                                          const float (&w)[KC], const float (&u)[KC]) {
    float z0  = fmaf(a0.x, w[C*16+0],  u[C*16+0]);
    float z1  = fmaf(a0.y, w[C*16+1],  u[C*16+1]);
    float z2  = fmaf(a0.z, w[C*16+2],  u[C*16+2]);
    float z3  = fmaf(a0.w, w[C*16+3],  u[C*16+3]);
    float z4  = fmaf(a1.x, w[C*16+4],  u[C*16+4]);
    float z5  = fmaf(a1.y, w[C*16+5],  u[C*16+5]);
    float z6  = fmaf(a1.z, w[C*16+6],  u[C*16+6]);
    float z7  = fmaf(a1.w, w[C*16+7],  u[C*16+7]);
    float z8  = fmaf(a2.x, w[C*16+8],  u[C*16+8]);
    float z9  = fmaf(a2.y, w[C*16+9],  u[C*16+9]);
    float z10 = fmaf(a2.z, w[C*16+10], u[C*16+10]);
    float z11 = fmaf(a2.w, w[C*16+11], u[C*16+11]);
    float z12 = fmaf(a3.x, w[C*16+12], u[C*16+12]);
    float z13 = fmaf(a3.y, w[C*16+13], u[C*16+13]);
    float z14 = fmaf(a3.z, w[C*16+14], u[C*16+14]);
    float z15 = fmaf(a3.w, w[C*16+15], u[C*16+15]);
    float p0 = (z0 * z1)   * (z2 * z3);
    float p1 = (z4 * z5)   * (z6 * z7);
    float p2 = (z8 * z9)   * (z10 * z11);
    float p3 = (z12 * z13) * (z14 * z15);
    return (p0 * p1) * (p2 * p3);
}

// Load 16-float chunk (bb, cc) of the staged x tile into 4 named float4s.
#define RD_CHUNK(d0, d1, d2, d3, bb, cc)                                   \
    {                                                                      \
        const float4* _p = sx4 + (bb) * 128 + kq0 + (cc) * 4;              \
        d0 = _p[0]; d1 = _p[1]; d2 = _p[2]; d3 = _p[3];                    \
    }

__global__ __launch_bounds__(512, 2)
void conj_kernel(const float* __restrict__ x,
                 const float* __restrict__ W,
                 float* __restrict__ out)
{
    __shared__ float s_x[NB * IDIM];     // staged x rows b0..b0+15, 32 KB
    __shared__ float s_p[NB * 8 * 64];   // [bi][wave][lane] partials, 32 KB

    const int tid  = threadIdx.x;
    const int lane = tid & 63;
    const int wv   = __builtin_amdgcn_readfirstlane(tid >> 6);   // 0..7, SGPR
    const int h    = blockIdx.x >> 8;        // j-half; pairs 256 apart -> same XCD
    const int bg   = blockIdx.x & (GB - 1);
    const int b0   = bg * NB;
    const int j    = h * 64 + lane;
    const int kq0  = wv * 16;                // wave's float4 offset within a row

    // ---- Stage x: 16 consecutive rows = 32 KB CONTIGUOUS global memory.
    // 512 threads x 4 dwordx4, perfectly coalesced.
    {
        const float4* gx = (const float4*)(x + (size_t)b0 * IDIM);  // 2048 float4
        float4* sx = (float4*)s_x;
        #pragma unroll
        for (int k = 0; k < 4; ++k)
            sx[tid + k * 512] = gx[tid + k * 512];
    }

    // ---- W fragment (overlaps the x staging latency): w = W[j, wv*64 ...],
    // u = 1 - w. 128 VGPRs, constant-index access only.
    float w[KC], u[KC];
    {
        const v4f* wp = (const v4f*)(W + (size_t)j * IDIM + wv * KC);
        #pragma unroll
        for (int qd = 0; qd < 16; ++qd) {
            v4f t = wp[qd];
            w[4 * qd + 0] = t.x;  u[4 * qd + 0] = 1.0f - t.x;
            w[4 * qd + 1] = t.y;  u[4 * qd + 1] = 1.0f - t.y;
            w[4 * qd + 2] = t.z;  u[4 * qd + 2] = 1.0f - t.z;
            w[4 * qd + 3] = t.w;  u[4 * qd + 3] = 1.0f - t.w;
        }
    }
    __syncthreads();

    const float4* sx4 = (const float4*)s_x;

    // ---- Distance-2 LDS prefetch pipeline over 64 chunks (16 bi x 4 c).
    float4 A0, A1, A2, A3, B0, B1, B2, B3;
    RD_CHUNK(A0, A1, A2, A3, 0, 0);
    RD_CHUNK(B0, B1, B2, B3, 0, 1);

    for (int bi = 0; bi < NB; ++bi) {
        const int nb = (bi + 1 == NB) ? NB - 1 : bi + 1;   // clamped prefetch row

        float pc0 = chunk16s<0>(A0, A1, A2, A3, w, u);
        RD_CHUNK(A0, A1, A2, A3, bi, 2);
        float pc1 = chunk16s<1>(B0, B1, B2, B3, w, u);
        RD_CHUNK(B0, B1, B2, B3, bi, 3);
        float pc2 = chunk16s<2>(A0, A1, A2, A3, w, u);
        RD_CHUNK(A0, A1, A2, A3, nb, 0);
        float pc3 = chunk16s<3>(B0, B1, B2, B3, w, u);
        RD_CHUNK(B0, B1, B2, B3, nb, 1);

        const float m = (pc0 * pc1) * (pc2 * pc3);
        // product of all 64 z's in (0.5^64, 1] -> one log2
        s_p[bi * 512 + wv * 64 + lane] = __builtin_amdgcn_logf(m);
    }
    __syncthreads();

    // ---- Reduce the 8 K-chunks, finalize, coalesced store. 2 outputs/thread.
    #pragma unroll
    for (int r = 0; r < (NB * 64) / 512; ++r) {
        const int idx = tid + r * 512;
        const int bi  = idx >> 6;
        const int l   = idx & 63;
        float sum = 0.0f;
        #pragma unroll
        for (int wq = 0; wq < 8; ++wq)
            sum += s_p[bi * 512 + wq * 64 + l];   // lanes consecutive: no conflict
        out[(size_t)(b0 + bi) * NOUT + h * 64 + l] = 1.0f / (1.0f - LN2 * sum);
    }
}

extern "C" void kernel_launch(void* const* d_in, const int* in_sizes, int n_in,
                              void* d_out, int out_size, void* d_ws, size_t ws_size,
                              hipStream_t stream) {
    const float* x = (const float*)d_in[0];   // (4096, 512) fp32
    const float* W = (const float*)d_in[1];   // (128, 512) fp32
    float* out = (float*)d_out;               // (4096, 128) fp32

    dim3 grid(2 * GB);                        // 512 blocks (j-half major)
    dim3 block(512);                          // 8 waves
    hipLaunchKernelGGL(conj_kernel, grid, block, 0, stream, x, W, out);
}